// Round 17
// baseline (133.369 us; speedup 1.0000x reference)
//
#include <hip/hip_runtime.h>
#include <hip/hip_bf16.h>

// Local-window attention, B=32 S=1024(16x64) H=8 D=384/8=48, window 7x11.
// R17: attn VALU-chain cuts — (a) exp2-fold: Q pre-scaled by log2e/sqrt(48)
//      in K1, softmax uses exp2f (1 v_exp, no mul), THR 8->11 (2^11 bound);
//      (b) v_cvt_pk_bf16_f32 (inline asm, m214v22-verified) for P pack and
//      O epilogue pack (1 instr per f32 pair vs ~8-op manual RNE).
//      K1/K3 = R16 8-wave (passing), everything else unchanged.

typedef __attribute__((ext_vector_type(8))) unsigned short ushort8;
typedef __attribute__((ext_vector_type(4))) unsigned short ushort4v;
typedef __attribute__((ext_vector_type(8))) short short8v;
typedef __attribute__((ext_vector_type(4))) float floatx4;

__device__ __forceinline__ float bf2f(unsigned short u) {
  union { unsigned int i; float f; } x;
  x.i = ((unsigned int)u) << 16;
  return x.f;
}

__device__ __forceinline__ unsigned short f2bu(float f) {
  union { float f; unsigned int i; } x;
  x.f = f;
  unsigned int lsb = (x.i >> 16) & 1u;
  x.i += 0x7FFFu + lsb;  // RNE
  return (unsigned short)(x.i >> 16);
}

__device__ __forceinline__ unsigned int cvtpk_bf16(float lo, float hi) {
  unsigned int r;
  asm("v_cvt_pk_bf16_f32 %0, %1, %2" : "=v"(r) : "v"(lo), "v"(hi));
  return r;
}

__device__ __forceinline__ void gload_lds16(const void* g, void* l) {
  __builtin_amdgcn_global_load_lds(
      (const __attribute__((address_space(1))) unsigned int*)g,
      (__attribute__((address_space(3))) unsigned int*)l, 16, 0, 0);
}

// ---------------- K0a: f32 -> bf16 ----------------
__global__ __launch_bounds__(256) void cvt_f32_bf16(
    const float4* __restrict__ in, ushort4v* __restrict__ out, int n4) {
  const int i = blockIdx.x * 256 + threadIdx.x;
  if (i < n4) {
    const float4 v = in[i];
    ushort4v o;
    o[0] = f2bu(v.x); o[1] = f2bu(v.y); o[2] = f2bu(v.z); o[3] = f2bu(v.w);
    out[i] = o;
  }
}

// ---------------- K0b/c: transpose f32 [R][C] -> bf16 [C][R] ----------------
__global__ __launch_bounds__(256) void transpose_cvt(
    const float* __restrict__ in, unsigned short* __restrict__ out, int R, int C) {
  __shared__ float t[32][33];
  const int c0 = blockIdx.x * 32, r0 = blockIdx.y * 32;
  const int tx = threadIdx.x, ty = threadIdx.y;
  #pragma unroll
  for (int rr = ty; rr < 32; rr += 8) t[rr][tx] = in[(size_t)(r0 + rr) * C + c0 + tx];
  __syncthreads();
  #pragma unroll
  for (int rr = ty; rr < 32; rr += 8)
    out[(size_t)(c0 + rr) * R + r0 + tx] = f2bu(t[tx][rr]);
}

// ---------------- MFMA GEMM: 8-wave 512-thread, BK=64 4-buffer loop ----------
// Same as R16 (passing). MODE 0: q pre-scaled by log2e/sqrt(48) for the
// exp2-based softmax in attn.
template <int MODE>
__global__ __launch_bounds__(512) void gemm_mfma(
    const unsigned short* __restrict__ A,   // [M][384] bf16
    const unsigned short* __restrict__ Bt,  // [N][384] bf16 (= B^T)
    const float* __restrict__ bias, float* __restrict__ outf,
    unsigned short* __restrict__ qws, unsigned short* __restrict__ kws,
    unsigned short* __restrict__ vtws)
{
  __shared__ unsigned short smem[32768];  // 64KB
  const int tid = threadIdx.x;
  const int lane = tid & 63, w = tid >> 6;
  const int wm = w & 3, wn = w >> 2;

  // chunked XCD swizzle
  const int nbx = gridDim.x;
  const int nwg = nbx * gridDim.y;
  const int bid = blockIdx.y * nbx + blockIdx.x;
  const int swz = (bid & 7) * (nwg >> 3) + (bid >> 3);
  const int n0 = (swz % nbx) * 128;
  const int m0 = (swz / nbx) * 128;

  floatx4 acc[2][4];
  #pragma unroll
  for (int mi = 0; mi < 2; ++mi)
    #pragma unroll
    for (int ni = 0; ni < 4; ++ni)
      acc[mi][ni] = (floatx4){0.f, 0.f, 0.f, 0.f};

  const int srow = tid >> 2;            // 0..127
  const int kslot16 = (tid & 3) * 16;

  auto ASB = [&](int buf) -> char* { return (char*)smem + buf * 8192; };
  auto BSB = [&](int buf) -> char* { return (char*)smem + 32768 + buf * 8192; };

  auto STAGE = [&](int buf, int k0) {
    const int kb = kslot16 ^ ((srow & 3) << 4);
    gload_lds16((const char*)A + (size_t)(m0 + srow) * 768 + k0 * 2 + kb,
                ASB(buf) + w * 1024);
    gload_lds16((const char*)Bt + (size_t)(n0 + srow) * 768 + k0 * 2 + kb,
                BSB(buf) + w * 1024);
  };

  auto COMPUTE = [&](int buf) {
    short8v a[2], b[4];
    const int kgb = (lane >> 4) * 16;
    #pragma unroll
    for (int mi = 0; mi < 2; ++mi) {
      const int r = wm * 32 + mi * 16 + (lane & 15);
      a[mi] = *reinterpret_cast<const short8v*>(
          ASB(buf) + r * 64 + (kgb ^ ((r & 3) << 4)));
    }
    #pragma unroll
    for (int ni = 0; ni < 4; ++ni) {
      const int r = wn * 64 + ni * 16 + (lane & 15);
      b[ni] = *reinterpret_cast<const short8v*>(
          BSB(buf) + r * 64 + (kgb ^ ((r & 3) << 4)));
    }
    #pragma unroll
    for (int mi = 0; mi < 2; ++mi)
      #pragma unroll
      for (int ni = 0; ni < 4; ++ni)
        acc[mi][ni] = __builtin_amdgcn_mfma_f32_16x16x32_bf16(
            a[mi], b[ni], acc[mi][ni], 0, 0, 0);
  };

  STAGE(0, 0);
  STAGE(1, 32);

  #pragma unroll
  for (int s = 0; s < 6; ++s) {
    const int rb = (s & 1) * 2;  // read bufs rb, rb+1 (tiles 2s, 2s+1)
    const int sb = rb ^ 2;       // stage bufs (tiles 2s+2, 2s+3)
    if (s < 5) {
      STAGE(sb, (2 * s + 2) * 32);
      STAGE(sb + 1, (2 * s + 3) * 32);
      asm volatile("s_waitcnt vmcnt(4)" ::: "memory");  // read-pair loads done
    } else {
      asm volatile("s_waitcnt vmcnt(0)" ::: "memory");
    }
    __builtin_amdgcn_s_barrier();
    __builtin_amdgcn_s_setprio(1);
    COMPUTE(rb);
    COMPUTE(rb + 1);
    __builtin_amdgcn_s_setprio(0);
    asm volatile("s_waitcnt lgkmcnt(0)" ::: "memory");
    __builtin_amdgcn_s_barrier();
  }

  const int col_l = lane & 15;
  const int row_l = (lane >> 4) * 4;

  if (MODE == 0) {
    // q scale = log2(e)/sqrt(48): softmax in attn uses exp2 directly.
    const float QSCALE = 0.20823555877171766f;
    const int which = n0 / 384;  // uniform per block (384 | 128*{0,3,6})
    if (which < 2) {
      // q/k: direct scatter (4x32B row segments per store — R13-proven)
      unsigned short* dstb = (which == 0) ? qws : kws;
      const float scale = (which == 0) ? QSCALE : 1.f;
      #pragma unroll
      for (int ni = 0; ni < 4; ++ni) {
        const int cg = n0 + wn * 64 + ni * 16 + col_l;
        const int rem = cg - which * 384;
        const int h = rem / 48;
        const int d = rem - h * 48;
        #pragma unroll
        for (int mi = 0; mi < 2; ++mi) {
          #pragma unroll
          for (int reg = 0; reg < 4; ++reg) {
            const int r = m0 + wm * 32 + mi * 16 + row_l + reg;
            const int bb = r >> 10, s = r & 1023;
            dstb[(((size_t)(bb * 8 + h)) * 1024 + s) * 48 + d] =
                f2bu(acc[mi][ni][reg] * scale);
          }
        }
      }
    } else {
      // V: transpose C-tile through LDS, coalesced vt writes (R11-verified)
      unsigned short* T = smem;  // 128*136 = 17408 shorts, aliases staging
      #pragma unroll
      for (int ni = 0; ni < 4; ++ni) {
        const int col = wn * 64 + ni * 16 + col_l;
        #pragma unroll
        for (int mi = 0; mi < 2; ++mi) {
          const int rowb = wm * 32 + mi * 16 + row_l;
          #pragma unroll
          for (int reg = 0; reg < 4; ++reg)
            T[col * 136 + rowb + reg] = f2bu(acc[mi][ni][reg]);
        }
      }
      __syncthreads();
      const int col = tid >> 2, q = tid & 3;
      const int cg = n0 + col;
      const int rem = cg - 768;
      const int h = rem / 48, d = rem - h * 48;
      const int bb = m0 >> 10;
      const int s0 = (m0 & 1023) + q * 32;
      unsigned short* dst =
          vtws + (((size_t)(bb * 8 + h)) * 48 + d) * 1024 + s0;
      const unsigned short* src = T + col * 136 + q * 32;
      #pragma unroll
      for (int j = 0; j < 4; ++j)
        *reinterpret_cast<ushort8*>(dst + j * 8) =
            *reinterpret_cast<const ushort8*>(src + j * 8);
    }
  } else {
    #pragma unroll
    for (int ni = 0; ni < 4; ++ni) {
      const int cg = n0 + wn * 64 + ni * 16 + col_l;
      const float bv = bias[cg];
      #pragma unroll
      for (int mi = 0; mi < 2; ++mi) {
        #pragma unroll
        for (int reg = 0; reg < 4; ++reg) {
          const int r = m0 + wm * 32 + mi * 16 + row_l + reg;
          outf[(size_t)r * 384 + cg] = acc[mi][ni][reg] + bv;
        }
      }
    }
  }
}

// ---------------- K2: MFMA local attention (exp2 + cvt_pk) ----------
__global__ __launch_bounds__(256) void attn_mfma(
    const unsigned short* __restrict__ qws,  // [bh][1024][48] (log2e-scaled q)
    const unsigned short* __restrict__ kws,  // [bh][1024][48]
    const unsigned short* __restrict__ vt,   // [bh][48][1024]
    unsigned short* __restrict__ attn_out)   // [b*1024][384] bf16
{
  __shared__ unsigned short plds_all[4 * 64 * 72];

  const int tid = threadIdx.x;
  const int w = tid >> 6;
  const int lane = tid & 63;
  const int blk = blockIdx.x;
  const int sw = ((blk & 7) << 7) | (blk >> 3);  // 1024 % 8 == 0
  const int task = sw * 4 + w;
  const int i  = task & 15;
  const int bh = task >> 4;
  const int ql = lane & 15;
  const int g  = lane >> 4;

  unsigned short* plds = plds_all + w * 4608;  // 64*72 per wave

  // zero plds once: band-external tiles stay 0 forever -> PV adds exact zeros
  {
    const uint4 zz = make_uint4(0, 0, 0, 0);
    #pragma unroll
    for (int z = 0; z < 9; ++z)
      reinterpret_cast<uint4*>(plds)[lane + z * 64] = zz;
  }

  const unsigned short* qbase = qws + (size_t)bh * 1024 * 48;
  const unsigned short* kbase = kws + (size_t)bh * 1024 * 48;
  const unsigned short* vbase = vt  + (size_t)bh * 48 * 1024;

  const short8v zfrag = (short8v){0, 0, 0, 0, 0, 0, 0, 0};

  short8v qf[4][2];
  #pragma unroll
  for (int qt = 0; qt < 4; ++qt) {
    const unsigned short* qrow = qbase + (size_t)(i * 64 + qt * 16 + ql) * 48;
    qf[qt][0] = *reinterpret_cast<const short8v*>(qrow + 8 * g);
    qf[qt][1] = (g < 2) ? *reinterpret_cast<const short8v*>(qrow + 32 + 8 * g)
                        : zfrag;
  }

  floatx4 ot[3][4];
  #pragma unroll
  for (int dt = 0; dt < 3; ++dt)
    #pragma unroll
    for (int qt = 0; qt < 4; ++qt)
      ot[dt][qt] = (floatx4){0.f, 0.f, 0.f, 0.f};
  float mreg[4] = {-INFINITY, -INFINITY, -INFINITY, -INFINITY};
  float lreg[4] = {0.f, 0.f, 0.f, 0.f};

  const int ki0 = (i - 3 < 0) ? 0 : i - 3;
  const int ki1 = (i + 3 > 15) ? 15 : i + 3;

  for (int ki = ki0; ki <= ki1; ++ki) {
    short8v kf[4][2];
    #pragma unroll
    for (int kt = 0; kt < 4; ++kt) {
      const unsigned short* krow = kbase + (size_t)(ki * 64 + kt * 16 + ql) * 48;
      kf[kt][0] = *reinterpret_cast<const short8v*>(krow + 8 * g);
      kf[kt][1] = (g < 2) ? *reinterpret_cast<const short8v*>(krow + 32 + 8 * g)
                          : zfrag;
    }
    short8v vf[3][2];
    #pragma unroll
    for (int dt = 0; dt < 3; ++dt)
      #pragma unroll
      for (int c = 0; c < 2; ++c)
        vf[dt][c] = *reinterpret_cast<const short8v*>(
            vbase + (size_t)(16 * dt + ql) * 1024 + ki * 64 + 32 * c + 8 * g);

    #pragma unroll
    for (int qt = 0; qt < 4; ++qt) {
      const int kts = (qt == 0) ? 0 : qt - 1;
      const int kte = (qt == 3) ? 3 : qt + 1;
      floatx4 s[4];
      #pragma unroll
      for (int kt = 0; kt < 4; ++kt) {
        if (kt < kts || kt > kte) continue;
        s[kt] = __builtin_amdgcn_mfma_f32_16x16x32_bf16(
            kf[kt][0], qf[qt][0], (floatx4){0.f, 0.f, 0.f, 0.f}, 0, 0, 0);
        s[kt] = __builtin_amdgcn_mfma_f32_16x16x32_bf16(
            kf[kt][1], qf[qt][1], s[kt], 0, 0, 0);
      }
      const int qcol = qt * 16 + ql;
      float pmax = -INFINITY;
      #pragma unroll
      for (int kt = 0; kt < 4; ++kt) {
        if (kt < kts || kt > kte) continue;
        #pragma unroll
        for (int r = 0; r < 4; ++r) {
          const int delta = kt * 16 + 4 * g + r - qcol;
          const bool ok = (delta <= 5) && (delta >= -5);
          s[kt][r] = ok ? s[kt][r] : -INFINITY;
          pmax = fmaxf(pmax, s[kt][r]);
        }
      }
      // defer-max in log2 units (first ki: m=-inf -> always initializes)
      if (!__all(pmax - mreg[qt] <= 11.0f)) {
        float mt = fmaxf(pmax, __shfl_xor(pmax, 16, 64));
        mt = fmaxf(mt, __shfl_xor(mt, 32, 64));
        const float mnew = fmaxf(mreg[qt], mt);
        const float corr = exp2f(mreg[qt] - mnew);  // exp2(-inf)=0 first time
        lreg[qt] *= corr;
        #pragma unroll
        for (int dt = 0; dt < 3; ++dt) {
          ot[dt][qt][0] *= corr; ot[dt][qt][1] *= corr;
          ot[dt][qt][2] *= corr; ot[dt][qt][3] *= corr;
        }
        mreg[qt] = mnew;
      }
      float ps = 0.f;
      #pragma unroll
      for (int kt = 0; kt < 4; ++kt) {
        if (kt < kts || kt > kte) continue;
        #pragma unroll
        for (int r = 0; r < 4; ++r) {
          const float p = exp2f(s[kt][r] - mreg[qt]);  // bounded by 2^11
          s[kt][r] = p;
          ps += p;
        }
      }
      ps += __shfl_xor(ps, 16, 64);
      ps += __shfl_xor(ps, 32, 64);
      lreg[qt] += ps;
      #pragma unroll
      for (int kt = 0; kt < 4; ++kt) {
        if (kt < kts || kt > kte) continue;
        uint2 pk;
        pk.x = cvtpk_bf16(s[kt][0], s[kt][1]);
        pk.y = cvtpk_bf16(s[kt][2], s[kt][3]);
        *reinterpret_cast<uint2*>(&plds[(qt * 16 + ql) * 72 + kt * 16 + 4 * g]) = pk;
      }
    }

    // PV band-skip: qt=0 band is k<32 (skip c=1); qt=3 band is k>=32 (skip c=0)
    __builtin_amdgcn_s_setprio(1);
    #pragma unroll
    for (int qt = 0; qt < 4; ++qt) {
      #pragma unroll
      for (int c = 0; c < 2; ++c) {
        if ((qt == 0 && c == 1) || (qt == 3 && c == 0)) continue;
        const short8v pf = *reinterpret_cast<const short8v*>(
            &plds[(qt * 16 + ql) * 72 + 32 * c + 8 * g]);
        #pragma unroll
        for (int dt = 0; dt < 3; ++dt)
          ot[dt][qt] = __builtin_amdgcn_mfma_f32_16x16x32_bf16(
              vf[dt][c], pf, ot[dt][qt], 0, 0, 0);
      }
    }
    __builtin_amdgcn_s_setprio(0);
  }

  // epilogue: normalize, store O^T -> attn_out[(b, i*64+q)][h*48 + d]
  const int b = bh >> 3, h = bh & 7;
  #pragma unroll
  for (int qt = 0; qt < 4; ++qt) {
    const float inv = 1.0f / lreg[qt];
    unsigned short* orow =
        attn_out + (size_t)(b * 1024 + i * 64 + qt * 16 + ql) * 384 + h * 48;
    #pragma unroll
    for (int dt = 0; dt < 3; ++dt) {
      const int d0 = 16 * dt + 4 * g;
      const unsigned int w0 = cvtpk_bf16(ot[dt][qt][0] * inv, ot[dt][qt][1] * inv);
      const unsigned int w1 = cvtpk_bf16(ot[dt][qt][2] * inv, ot[dt][qt][3] * inv);
      *reinterpret_cast<unsigned int*>(orow + d0)     = w0;
      *reinterpret_cast<unsigned int*>(orow + d0 + 2) = w1;
    }
  }
}

extern "C" void kernel_launch(void* const* d_in, const int* in_sizes, int n_in,
                              void* d_out, int out_size, void* d_ws, size_t ws_size,
                              hipStream_t stream) {
  const float* x      = (const float*)d_in[0];
  const float* w_qkv  = (const float*)d_in[1];
  const float* w_proj = (const float*)d_in[2];
  const float* b_proj = (const float*)d_in[3];
  // d_in[4] (mask) unused: window is analytic (|di|<=3, |dj|<=5)

  const size_t T = 25165824;  // 32768*384*2 bytes
  char* ws = (char*)d_ws;
  unsigned short* xb    = (unsigned short*)ws;            // aliased with attn_out
  unsigned short* qws   = (unsigned short*)(ws + T);
  unsigned short* kws   = (unsigned short*)(ws + 2 * T);
  unsigned short* vtws  = (unsigned short*)(ws + 3 * T);  // [bh][48][1024]
  unsigned short* wqkvT = (unsigned short*)(ws + 4 * T);
  unsigned short* wpT   = (unsigned short*)(ws + 4 * T + 884736);
  unsigned short* attn_out = xb;  // xb dead after K1
  float* out = (float*)d_out;

  // K0: conversions
  cvt_f32_bf16<<<12288, 256, 0, stream>>>((const float4*)x, (ushort4v*)xb, 3145728);
  transpose_cvt<<<dim3(36, 12), dim3(32, 8), 0, stream>>>(w_qkv, wqkvT, 384, 1152);
  transpose_cvt<<<dim3(12, 12), dim3(32, 8), 0, stream>>>(w_proj, wpT, 384, 384);

  // K1: qkv GEMM (M=32768, K=384, N=1152) -> q/k [bh][s][48], v^T [bh][48][s]
  gemm_mfma<0><<<dim3(9, 256), 512, 0, stream>>>(xb, wqkvT, nullptr, nullptr,
                                                 qws, kws, vtws);
  // K2: MFMA local attention -> attn_out bf16 [B*S, 384]
  attn_mfma<<<dim3(1024), 256, 0, stream>>>(qws, kws, vtws, attn_out);
  // K3: out = attn_out @ w_proj + bias (N=384), f32 out
  gemm_mfma<1><<<dim3(3, 256), 512, 0, stream>>>(attn_out, wpT, b_proj, out,
                                                 nullptr, nullptr, nullptr);
}

// Round 18
// 131.019 us; speedup vs baseline: 1.0179x; 1.0179x over previous
//
#include <hip/hip_runtime.h>
#include <hip/hip_bf16.h>

// Local-window attention, B=32 S=1024(16x64) H=8 D=384/8=48, window 7x11.
// R18: fuse x f32->bf16 conversion INTO K1 (drop the 12us cvt kernel).
//      K1 A-staging = reg-staged: 2x dwordx4 f32 loads/thread/tile ->
//      v_cvt_pk_bf16_f32 -> ds_write_b128 into the SAME swizzled LDS layout
//      (LDS[row][slot^swz] = x[row][slot]; read side unchanged). B staging
//      stays global_load_lds. Write-late schedule, derived vmcnt counts.
//      attn reverted to R16 (best: 51us). K3 = R16 MODE 1 (unchanged).

typedef __attribute__((ext_vector_type(8))) unsigned short ushort8;
typedef __attribute__((ext_vector_type(8))) short short8v;
typedef __attribute__((ext_vector_type(4))) float floatx4;

__device__ __forceinline__ float bf2f(unsigned short u) {
  union { unsigned int i; float f; } x;
  x.i = ((unsigned int)u) << 16;
  return x.f;
}

__device__ __forceinline__ unsigned short f2bu(float f) {
  union { float f; unsigned int i; } x;
  x.f = f;
  unsigned int lsb = (x.i >> 16) & 1u;
  x.i += 0x7FFFu + lsb;  // RNE
  return (unsigned short)(x.i >> 16);
}

__device__ __forceinline__ unsigned int cvtpk_bf16(float lo, float hi) {
  unsigned int r;
  asm("v_cvt_pk_bf16_f32 %0, %1, %2" : "=v"(r) : "v"(lo), "v"(hi));
  return r;
}

__device__ __forceinline__ void gload_lds16(const void* g, void* l) {
  __builtin_amdgcn_global_load_lds(
      (const __attribute__((address_space(1))) unsigned int*)g,
      (__attribute__((address_space(3))) unsigned int*)l, 16, 0, 0);
}

// ---------------- K0b/c: transpose f32 [R][C] -> bf16 [C][R] ----------------
__global__ __launch_bounds__(256) void transpose_cvt(
    const float* __restrict__ in, unsigned short* __restrict__ out, int R, int C) {
  __shared__ float t[32][33];
  const int c0 = blockIdx.x * 32, r0 = blockIdx.y * 32;
  const int tx = threadIdx.x, ty = threadIdx.y;
  #pragma unroll
  for (int rr = ty; rr < 32; rr += 8) t[rr][tx] = in[(size_t)(r0 + rr) * C + c0 + tx];
  __syncthreads();
  #pragma unroll
  for (int rr = ty; rr < 32; rr += 8)
    out[(size_t)(c0 + rr) * R + r0 + tx] = f2bu(t[tx][rr]);
}

// ---------------- K1: fused qkv GEMM, A = x (f32), reg-staged ----------------
// 128x128 tile, 8 waves x 512 thr, BK=64 pairs, 4 LDS bufs (pair p -> bufs
// {2*(p&1), 2*(p&1)+1}). Thread t: arow=t>>2, aslot=t&3 (16B bf16 chunk).
// Schedule per iter s (compute pair Ps): COMPUTE -> lgkm(0) -> vmcnt(4)
// [drains B(Ps+1)] -> barrier -> {Bgload(Ps+2), vmcnt(2) [A regs], dswrite
// A(Ps+2), loadA(Ps+3)}. Prologue stages P0,P1 + loads P2.
__global__ __launch_bounds__(512) void gemm_qkv(
    const float* __restrict__ X,             // [32768][384] f32
    const unsigned short* __restrict__ Bt,   // [1152][384] bf16 (w_qkv^T)
    unsigned short* __restrict__ qws, unsigned short* __restrict__ kws,
    unsigned short* __restrict__ vtws)
{
  __shared__ unsigned short smem[32768];  // 64KB: A bufs 0..32KB, B 32..64KB
  const int tid = threadIdx.x;
  const int lane = tid & 63, w = tid >> 6;
  const int wm = w & 3, wn = w >> 2;

  const int nbx = gridDim.x;
  const int nwg = nbx * gridDim.y;
  const int bid = blockIdx.y * nbx + blockIdx.x;
  const int swz = (bid & 7) * (nwg >> 3) + (bid >> 3);
  const int n0 = (swz % nbx) * 128;
  const int m0 = (swz / nbx) * 128;

  floatx4 acc[2][4];
  #pragma unroll
  for (int mi = 0; mi < 2; ++mi)
    #pragma unroll
    for (int ni = 0; ni < 4; ++ni)
      acc[mi][ni] = (floatx4){0.f, 0.f, 0.f, 0.f};

  const int arow = tid >> 2;          // 0..127
  const int aslot = tid & 3;          // 16B bf16 chunk within row
  const int adst = arow * 64 + ((aslot * 16) ^ ((arow & 3) << 4));  // byte
  const float* asrc = X + (size_t)(m0 + arow) * 384 + aslot * 8;

  auto ASB = [&](int buf) -> char* { return (char*)smem + buf * 8192; };
  auto BSB = [&](int buf) -> char* { return (char*)smem + 32768 + buf * 8192; };

  float4 bank0[4], bank1[4];  // A f32 regs: one PAIR (2 tiles x 8 floats)

  auto LOADA = [&](float4* bank, int p) {
    #pragma unroll
    for (int tile = 0; tile < 2; ++tile) {
      const float* s = asrc + (p * 2 + tile) * 32;
      bank[tile * 2 + 0] = *reinterpret_cast<const float4*>(s);
      bank[tile * 2 + 1] = *reinterpret_cast<const float4*>(s + 4);
    }
  };
  auto DSWRITE = [&](const float4* bank, int p) {
    #pragma unroll
    for (int tile = 0; tile < 2; ++tile) {
      const float4 f0 = bank[tile * 2 + 0];
      const float4 f1 = bank[tile * 2 + 1];
      uint4 v;
      v.x = cvtpk_bf16(f0.x, f0.y); v.y = cvtpk_bf16(f0.z, f0.w);
      v.z = cvtpk_bf16(f1.x, f1.y); v.w = cvtpk_bf16(f1.z, f1.w);
      *reinterpret_cast<uint4*>(ASB(2 * (p & 1) + tile) + adst) = v;
    }
  };
  const int srow = tid >> 2;
  const int kslot16 = (tid & 3) * 16;
  auto BGLOAD = [&](int p) {
    #pragma unroll
    for (int tile = 0; tile < 2; ++tile) {
      const int t = p * 2 + tile;
      const int kb = kslot16 ^ ((srow & 3) << 4);
      gload_lds16((const char*)Bt + (size_t)(n0 + srow) * 768 + t * 64 + kb,
                  BSB(2 * (p & 1) + tile) + w * 1024);
    }
  };
  auto COMPUTE = [&](int buf) {
    short8v a[2], b[4];
    const int kgb = (lane >> 4) * 16;
    #pragma unroll
    for (int mi = 0; mi < 2; ++mi) {
      const int r = wm * 32 + mi * 16 + (lane & 15);
      a[mi] = *reinterpret_cast<const short8v*>(
          ASB(buf) + r * 64 + (kgb ^ ((r & 3) << 4)));
    }
    #pragma unroll
    for (int ni = 0; ni < 4; ++ni) {
      const int r = wn * 64 + ni * 16 + (lane & 15);
      b[ni] = *reinterpret_cast<const short8v*>(
          BSB(buf) + r * 64 + (kgb ^ ((r & 3) << 4)));
    }
    #pragma unroll
    for (int mi = 0; mi < 2; ++mi)
      #pragma unroll
      for (int ni = 0; ni < 4; ++ni)
        acc[mi][ni] = __builtin_amdgcn_mfma_f32_16x16x32_bf16(
            a[mi], b[ni], acc[mi][ni], 0, 0, 0);
  };

  // ---- prologue: stage P0, P1; load A(P2) ----
  LOADA(bank0, 0);                     // A(P0): 4 loads
  BGLOAD(0);                           // B(P0): 2
  LOADA(bank1, 1);                     // A(P1): 4
  BGLOAD(1);                           // B(P1): 2   (12 outstanding)
  asm volatile("s_waitcnt vmcnt(8)" ::: "memory");   // A(P0) done
  DSWRITE(bank0, 0);
  asm volatile("s_waitcnt vmcnt(2)" ::: "memory");   // A(P1)+B(P0) done
  DSWRITE(bank1, 1);
  LOADA(bank0, 2);                     // A(P2): 4  (outst: B(P1)2 + A(P2)4)
  asm volatile("s_waitcnt lgkmcnt(0)" ::: "memory");
  __builtin_amdgcn_s_barrier();        // P0 visible

  #pragma unroll
  for (int s = 0; s < 6; ++s) {
    __builtin_amdgcn_s_setprio(1);
    COMPUTE(2 * (s & 1));
    COMPUTE(2 * (s & 1) + 1);
    __builtin_amdgcn_s_setprio(0);
    asm volatile("s_waitcnt lgkmcnt(0)" ::: "memory");
    if (s + 2 <= 5) {
      asm volatile("s_waitcnt vmcnt(4)" ::: "memory");  // B(Ps+1) landed
    } else if (s + 1 <= 5) {
      asm volatile("s_waitcnt vmcnt(0)" ::: "memory");  // B(P5) landed
    }
    __builtin_amdgcn_s_barrier();      // pair s&1 free; P(s+1) visible
    if (s + 2 <= 5) {
      BGLOAD(s + 2);
      asm volatile("s_waitcnt vmcnt(2)" ::: "memory");  // A(Ps+2) regs ready
      DSWRITE((s & 1) ? bank1 : bank0, s + 2);
      if (s + 3 <= 5) LOADA((s & 1) ? bank0 : bank1, s + 3);
    }
  }

  const int col_l = lane & 15;
  const int row_l = (lane >> 4) * 4;
  const float QSCALE = 0.14433756729740643f;  // 1/sqrt(48)
  const int which = n0 / 384;  // uniform per block

  if (which < 2) {
    unsigned short* dstb = (which == 0) ? qws : kws;
    const float scale = (which == 0) ? QSCALE : 1.f;
    #pragma unroll
    for (int ni = 0; ni < 4; ++ni) {
      const int cg = n0 + wn * 64 + ni * 16 + col_l;
      const int rem = cg - which * 384;
      const int h = rem / 48;
      const int d = rem - h * 48;
      #pragma unroll
      for (int mi = 0; mi < 2; ++mi) {
        #pragma unroll
        for (int reg = 0; reg < 4; ++reg) {
          const int r = m0 + wm * 32 + mi * 16 + row_l + reg;
          const int bb = r >> 10, s = r & 1023;
          dstb[(((size_t)(bb * 8 + h)) * 1024 + s) * 48 + d] =
              f2bu(acc[mi][ni][reg] * scale);
        }
      }
    }
  } else {
    // V: transpose C-tile through LDS, coalesced vt writes
    unsigned short* T = smem;  // aliases dead staging
    #pragma unroll
    for (int ni = 0; ni < 4; ++ni) {
      const int col = wn * 64 + ni * 16 + col_l;
      #pragma unroll
      for (int mi = 0; mi < 2; ++mi) {
        const int rowb = wm * 32 + mi * 16 + row_l;
        #pragma unroll
        for (int reg = 0; reg < 4; ++reg)
          T[col * 136 + rowb + reg] = f2bu(acc[mi][ni][reg]);
      }
    }
    __syncthreads();
    const int col = tid >> 2, q = tid & 3;
    const int cg = n0 + col;
    const int rem = cg - 768;
    const int h = rem / 48, d = rem - h * 48;
    const int bb = m0 >> 10;
    const int s0 = (m0 & 1023) + q * 32;
    unsigned short* dst =
        vtws + (((size_t)(bb * 8 + h)) * 48 + d) * 1024 + s0;
    const unsigned short* src = T + col * 136 + q * 32;
    #pragma unroll
    for (int j = 0; j < 4; ++j)
      *reinterpret_cast<ushort8*>(dst + j * 8) =
          *reinterpret_cast<const ushort8*>(src + j * 8);
  }
}

// ---------------- K3: proj GEMM (R16 8-wave, bf16 A via gload_lds) ----------
__global__ __launch_bounds__(512) void gemm_proj(
    const unsigned short* __restrict__ A,   // [32768][384] bf16 (attn_out)
    const unsigned short* __restrict__ Bt,  // [384][384] bf16 (w_proj^T)
    const float* __restrict__ bias, float* __restrict__ outf)
{
  __shared__ unsigned short smem[32768];
  const int tid = threadIdx.x;
  const int lane = tid & 63, w = tid >> 6;
  const int wm = w & 3, wn = w >> 2;

  const int nbx = gridDim.x;
  const int nwg = nbx * gridDim.y;
  const int bid = blockIdx.y * nbx + blockIdx.x;
  const int swz = (bid & 7) * (nwg >> 3) + (bid >> 3);
  const int n0 = (swz % nbx) * 128;
  const int m0 = (swz / nbx) * 128;

  floatx4 acc[2][4];
  #pragma unroll
  for (int mi = 0; mi < 2; ++mi)
    #pragma unroll
    for (int ni = 0; ni < 4; ++ni)
      acc[mi][ni] = (floatx4){0.f, 0.f, 0.f, 0.f};

  const int srow = tid >> 2;
  const int kslot16 = (tid & 3) * 16;

  auto ASB = [&](int buf) -> char* { return (char*)smem + buf * 8192; };
  auto BSB = [&](int buf) -> char* { return (char*)smem + 32768 + buf * 8192; };

  auto STAGE = [&](int buf, int k0) {
    const int kb = kslot16 ^ ((srow & 3) << 4);
    gload_lds16((const char*)A + (size_t)(m0 + srow) * 768 + k0 * 2 + kb,
                ASB(buf) + w * 1024);
    gload_lds16((const char*)Bt + (size_t)(n0 + srow) * 768 + k0 * 2 + kb,
                BSB(buf) + w * 1024);
  };

  auto COMPUTE = [&](int buf) {
    short8v a[2], b[4];
    const int kgb = (lane >> 4) * 16;
    #pragma unroll
    for (int mi = 0; mi < 2; ++mi) {
      const int r = wm * 32 + mi * 16 + (lane & 15);
      a[mi] = *reinterpret_cast<const short8v*>(
          ASB(buf) + r * 64 + (kgb ^ ((r & 3) << 4)));
    }
    #pragma unroll
    for (int ni = 0; ni < 4; ++ni) {
      const int r = wn * 64 + ni * 16 + (lane & 15);
      b[ni] = *reinterpret_cast<const short8v*>(
          BSB(buf) + r * 64 + (kgb ^ ((r & 3) << 4)));
    }
    #pragma unroll
    for (int mi = 0; mi < 2; ++mi)
      #pragma unroll
      for (int ni = 0; ni < 4; ++ni)
        acc[mi][ni] = __builtin_amdgcn_mfma_f32_16x16x32_bf16(
            a[mi], b[ni], acc[mi][ni], 0, 0, 0);
  };

  STAGE(0, 0);
  STAGE(1, 32);

  #pragma unroll
  for (int s = 0; s < 6; ++s) {
    const int rb = (s & 1) * 2;
    const int sb = rb ^ 2;
    if (s < 5) {
      STAGE(sb, (2 * s + 2) * 32);
      STAGE(sb + 1, (2 * s + 3) * 32);
      asm volatile("s_waitcnt vmcnt(4)" ::: "memory");
    } else {
      asm volatile("s_waitcnt vmcnt(0)" ::: "memory");
    }
    __builtin_amdgcn_s_barrier();
    __builtin_amdgcn_s_setprio(1);
    COMPUTE(rb);
    COMPUTE(rb + 1);
    __builtin_amdgcn_s_setprio(0);
    asm volatile("s_waitcnt lgkmcnt(0)" ::: "memory");
    __builtin_amdgcn_s_barrier();
  }

  const int col_l = lane & 15;
  const int row_l = (lane >> 4) * 4;
  #pragma unroll
  for (int ni = 0; ni < 4; ++ni) {
    const int cg = n0 + wn * 64 + ni * 16 + col_l;
    const float bv = bias[cg];
    #pragma unroll
    for (int mi = 0; mi < 2; ++mi) {
      #pragma unroll
      for (int reg = 0; reg < 4; ++reg) {
        const int r = m0 + wm * 32 + mi * 16 + row_l + reg;
        outf[(size_t)r * 384 + cg] = acc[mi][ni][reg] + bv;
      }
    }
  }
}

// ---------------- K2: MFMA local attention (R16 version, best measured) ----
__global__ __launch_bounds__(256) void attn_mfma(
    const unsigned short* __restrict__ qws,  // [bh][1024][48]
    const unsigned short* __restrict__ kws,  // [bh][1024][48]
    const unsigned short* __restrict__ vt,   // [bh][48][1024]
    unsigned short* __restrict__ attn_out)   // [b*1024][384] bf16
{
  __shared__ unsigned short plds_all[4 * 64 * 72];

  const int tid = threadIdx.x;
  const int w = tid >> 6;
  const int lane = tid & 63;
  const int blk = blockIdx.x;
  const int sw = ((blk & 7) << 7) | (blk >> 3);  // 1024 % 8 == 0
  const int task = sw * 4 + w;
  const int i  = task & 15;
  const int bh = task >> 4;
  const int ql = lane & 15;
  const int g  = lane >> 4;

  unsigned short* plds = plds_all + w * 4608;

  {
    const uint4 zz = make_uint4(0, 0, 0, 0);
    #pragma unroll
    for (int z = 0; z < 9; ++z)
      reinterpret_cast<uint4*>(plds)[lane + z * 64] = zz;
  }

  const unsigned short* qbase = qws + (size_t)bh * 1024 * 48;
  const unsigned short* kbase = kws + (size_t)bh * 1024 * 48;
  const unsigned short* vbase = vt  + (size_t)bh * 48 * 1024;

  const short8v zfrag = (short8v){0, 0, 0, 0, 0, 0, 0, 0};

  short8v qf[4][2];
  #pragma unroll
  for (int qt = 0; qt < 4; ++qt) {
    const unsigned short* qrow = qbase + (size_t)(i * 64 + qt * 16 + ql) * 48;
    qf[qt][0] = *reinterpret_cast<const short8v*>(qrow + 8 * g);
    qf[qt][1] = (g < 2) ? *reinterpret_cast<const short8v*>(qrow + 32 + 8 * g)
                        : zfrag;
  }

  floatx4 ot[3][4];
  #pragma unroll
  for (int dt = 0; dt < 3; ++dt)
    #pragma unroll
    for (int qt = 0; qt < 4; ++qt)
      ot[dt][qt] = (floatx4){0.f, 0.f, 0.f, 0.f};
  float mreg[4] = {-INFINITY, -INFINITY, -INFINITY, -INFINITY};
  float lreg[4] = {0.f, 0.f, 0.f, 0.f};

  const int ki0 = (i - 3 < 0) ? 0 : i - 3;
  const int ki1 = (i + 3 > 15) ? 15 : i + 3;

  for (int ki = ki0; ki <= ki1; ++ki) {
    short8v kf[4][2];
    #pragma unroll
    for (int kt = 0; kt < 4; ++kt) {
      const unsigned short* krow = kbase + (size_t)(ki * 64 + kt * 16 + ql) * 48;
      kf[kt][0] = *reinterpret_cast<const short8v*>(krow + 8 * g);
      kf[kt][1] = (g < 2) ? *reinterpret_cast<const short8v*>(krow + 32 + 8 * g)
                          : zfrag;
    }
    short8v vf[3][2];
    #pragma unroll
    for (int dt = 0; dt < 3; ++dt)
      #pragma unroll
      for (int c = 0; c < 2; ++c)
        vf[dt][c] = *reinterpret_cast<const short8v*>(
            vbase + (size_t)(16 * dt + ql) * 1024 + ki * 64 + 32 * c + 8 * g);

    #pragma unroll
    for (int qt = 0; qt < 4; ++qt) {
      const int kts = (qt == 0) ? 0 : qt - 1;
      const int kte = (qt == 3) ? 3 : qt + 1;
      floatx4 s[4];
      #pragma unroll
      for (int kt = 0; kt < 4; ++kt) {
        if (kt < kts || kt > kte) continue;
        s[kt] = __builtin_amdgcn_mfma_f32_16x16x32_bf16(
            kf[kt][0], qf[qt][0], (floatx4){0.f, 0.f, 0.f, 0.f}, 0, 0, 0);
        s[kt] = __builtin_amdgcn_mfma_f32_16x16x32_bf16(
            kf[kt][1], qf[qt][1], s[kt], 0, 0, 0);
      }
      const int qcol = qt * 16 + ql;
      float pmax = -INFINITY;
      #pragma unroll
      for (int kt = 0; kt < 4; ++kt) {
        if (kt < kts || kt > kte) continue;
        #pragma unroll
        for (int r = 0; r < 4; ++r) {
          const int delta = kt * 16 + 4 * g + r - qcol;
          const bool ok = (delta <= 5) && (delta >= -5);
          s[kt][r] = ok ? s[kt][r] : -INFINITY;
          pmax = fmaxf(pmax, s[kt][r]);
        }
      }
      if (!__all(pmax - mreg[qt] <= 8.0f)) {
        float mt = fmaxf(pmax, __shfl_xor(pmax, 16, 64));
        mt = fmaxf(mt, __shfl_xor(mt, 32, 64));
        const float mnew = fmaxf(mreg[qt], mt);
        const float corr = __expf(mreg[qt] - mnew);
        lreg[qt] *= corr;
        #pragma unroll
        for (int dt = 0; dt < 3; ++dt) {
          ot[dt][qt][0] *= corr; ot[dt][qt][1] *= corr;
          ot[dt][qt][2] *= corr; ot[dt][qt][3] *= corr;
        }
        mreg[qt] = mnew;
      }
      float ps = 0.f;
      #pragma unroll
      for (int kt = 0; kt < 4; ++kt) {
        if (kt < kts || kt > kte) continue;
        #pragma unroll
        for (int r = 0; r < 4; ++r) {
          const float p = __expf(s[kt][r] - mreg[qt]);
          s[kt][r] = p;
          ps += p;
        }
      }
      ps += __shfl_xor(ps, 16, 64);
      ps += __shfl_xor(ps, 32, 64);
      lreg[qt] += ps;
      #pragma unroll
      for (int kt = 0; kt < 4; ++kt) {
        if (kt < kts || kt > kte) continue;
        uint2 pk;
        pk.x = (unsigned int)f2bu(s[kt][0]) | ((unsigned int)f2bu(s[kt][1]) << 16);
        pk.y = (unsigned int)f2bu(s[kt][2]) | ((unsigned int)f2bu(s[kt][3]) << 16);
        *reinterpret_cast<uint2*>(&plds[(qt * 16 + ql) * 72 + kt * 16 + 4 * g]) = pk;
      }
    }

    __builtin_amdgcn_s_setprio(1);
    #pragma unroll
    for (int qt = 0; qt < 4; ++qt) {
      #pragma unroll
      for (int c = 0; c < 2; ++c) {
        if ((qt == 0 && c == 1) || (qt == 3 && c == 0)) continue;
        const short8v pf = *reinterpret_cast<const short8v*>(
            &plds[(qt * 16 + ql) * 72 + 32 * c + 8 * g]);
        #pragma unroll
        for (int dt = 0; dt < 3; ++dt)
          ot[dt][qt] = __builtin_amdgcn_mfma_f32_16x16x32_bf16(
              vf[dt][c], pf, ot[dt][qt], 0, 0, 0);
      }
    }
    __builtin_amdgcn_s_setprio(0);
  }

  const int b = bh >> 3, h = bh & 7;
  #pragma unroll
  for (int qt = 0; qt < 4; ++qt) {
    const float inv = 1.0f / lreg[qt];
    unsigned short* orow =
        attn_out + (size_t)(b * 1024 + i * 64 + qt * 16 + ql) * 384 + h * 48;
    #pragma unroll
    for (int dt = 0; dt < 3; ++dt) {
      const int d0 = 16 * dt + 4 * g;
      unsigned int w0 = (unsigned int)f2bu(ot[dt][qt][0] * inv) |
                        ((unsigned int)f2bu(ot[dt][qt][1] * inv) << 16);
      unsigned int w1 = (unsigned int)f2bu(ot[dt][qt][2] * inv) |
                        ((unsigned int)f2bu(ot[dt][qt][3] * inv) << 16);
      *reinterpret_cast<unsigned int*>(orow + d0)     = w0;
      *reinterpret_cast<unsigned int*>(orow + d0 + 2) = w1;
    }
  }
}

extern "C" void kernel_launch(void* const* d_in, const int* in_sizes, int n_in,
                              void* d_out, int out_size, void* d_ws, size_t ws_size,
                              hipStream_t stream) {
  const float* x      = (const float*)d_in[0];
  const float* w_qkv  = (const float*)d_in[1];
  const float* w_proj = (const float*)d_in[2];
  const float* b_proj = (const float*)d_in[3];
  // d_in[4] (mask) unused: window is analytic (|di|<=3, |dj|<=5)

  const size_t T = 25165824;  // 32768*384*2 bytes
  char* ws = (char*)d_ws;
  unsigned short* attn_out = (unsigned short*)ws;         // [B*S][384] bf16
  unsigned short* qws   = (unsigned short*)(ws + T);
  unsigned short* kws   = (unsigned short*)(ws + 2 * T);
  unsigned short* vtws  = (unsigned short*)(ws + 3 * T);  // [bh][48][1024]
  unsigned short* wqkvT = (unsigned short*)(ws + 4 * T);
  unsigned short* wpT   = (unsigned short*)(ws + 4 * T + 884736);
  float* out = (float*)d_out;

  // K0: weight transposes (x conversion now fused into K1)
  transpose_cvt<<<dim3(36, 12), dim3(32, 8), 0, stream>>>(w_qkv, wqkvT, 384, 1152);
  transpose_cvt<<<dim3(12, 12), dim3(32, 8), 0, stream>>>(w_proj, wpT, 384, 384);

  // K1: fused qkv GEMM (A = x f32) -> q/k [bh][s][48], v^T [bh][48][s]
  gemm_qkv<<<dim3(9, 256), 512, 0, stream>>>(x, wqkvT, qws, kws, vtws);
  // K2: MFMA local attention -> attn_out bf16 [B*S, 384]
  attn_mfma<<<dim3(1024), 256, 0, stream>>>(qws, kws, vtws, attn_out);
  // K3: out = attn_out @ w_proj + bias (N=384), f32 out
  gemm_proj<<<dim3(3, 256), 512, 0, stream>>>(attn_out, wpT, b_proj, out);
}